// Round 12
// baseline (547.151 us; speedup 1.0000x reference)
//
#include <hip/hip_runtime.h>

// ---------------- problem constants ----------------
#define B_SAMPLES 8192
#define HID       512
#define NCLS      10
#define STYLE_D   64
#define LATENT_D  16

#define BM 128
#define BN 64
#define BK 64
#define TRTILES (B_SAMPLES/BM)            // 64 trunk row tiles
#define MAXT    (TRTILES + NCLS)          // 74 worst-case expert row tiles
#define MAXROWS (B_SAMPLES + NCLS*BM)     // 9472 padded sorted rows
#define NCNT    (6*128 + 1)               // sync counters (+1 = global)

typedef short v8s __attribute__((ext_vector_type(8)));
typedef float v4f __attribute__((ext_vector_type(4)));

__device__ __forceinline__ short f2bf(float f) {
    union { float f; unsigned u; } x; x.f = f;
    unsigned r = x.u + 0x7fffu + ((x.u >> 16) & 1u);   // RNE; inputs finite
    return (short)(r >> 16);
}

__device__ __forceinline__ void gload16(const short* g, short* l) {
    __builtin_amdgcn_global_load_lds(
        (const __attribute__((address_space(1))) void*)g,
        (__attribute__((address_space(3))) void*)l, 16, 0, 0);
}

// global pre-swizzle: within each 64-elem slice of a row, XOR the 16B chunk
// index with (row&7). Writers store swizzled; global_load_lds copies rows
// linearly; fragment ds_reads XOR the same key (rule #21: both sides).
__device__ __forceinline__ int kswz(int row, int k) {
    return (k & ~63) + ((((k >> 3) & 7) ^ (row & 7)) << 3) + (k & 7);
}
__device__ __forceinline__ int cswz(int key, int n0, int c) {
    return n0 + ((((c >> 3) ^ key) & 7) << 3) + (c & 7);
}

// ---------------- sync primitives (agent scope: XCD-safe) ----------------
__device__ __forceinline__ void sig(int* c) {
    __syncthreads();                       // all stores of this block retired
    if (threadIdx.x == 0)
        __hip_atomic_fetch_add(c, 1, __ATOMIC_RELEASE, __HIP_MEMORY_SCOPE_AGENT);
}
__device__ __forceinline__ void waitc(int* c, int tgt) {
    if (threadIdx.x == 0)
        while (__hip_atomic_load(c, __ATOMIC_ACQUIRE, __HIP_MEMORY_SCOPE_AGENT) < tgt)
            __builtin_amdgcn_s_sleep(16);
    __syncthreads();
}

// ---------------- grouping + counter zeroing (one block) ----------------
__global__ void build_groups(const int* __restrict__ y, int* __restrict__ tclass,
                             int* __restrict__ trow0, int* __restrict__ order,
                             int* __restrict__ rank, int* __restrict__ cnt) {
    __shared__ int scnt[NCLS], cur[NCLS];
    int t = threadIdx.x;                       // 1024 threads
    if (t < NCLS) scnt[t] = 0;
    for (int i = t; i < NCNT; i += 1024) cnt[i] = 0;   // re-zero EVERY call
    __syncthreads();
    for (int b = t; b < B_SAMPLES; b += 1024) atomicAdd(&scnt[y[b]], 1);
    __syncthreads();
    if (t == 0) {
        int off = 0, tt = 0;
        for (int c = 0; c < NCLS; ++c) {
            cur[c] = off;
            int nt = (scnt[c] + BM - 1) / BM;
            for (int j = 0; j < nt; ++j) { tclass[tt] = c; trow0[tt] = off + j * BM; ++tt; }
            off += nt * BM;
        }
        for (int u = tt; u < MAXT; ++u) { tclass[u] = -1; trow0[u] = 0; }
    }
    __syncthreads();
    for (int i = t; i < MAXROWS; i += 1024) order[i] = -1;
    __syncthreads();
    for (int b = t; b < B_SAMPLES; b += 1024) {
        int c = y[b];
        int p = atomicAdd(&cur[c], 1);
        order[p] = b;
        rank[b] = p;
    }
}

// mega transpose -> bf16 [n][k], PRE-SWIZZLED rows. grid (20,16,36).
__global__ void transpose_mega(const float* __restrict__ z,
                               const float* __restrict__ sw0, const float* __restrict__ sw1,
                               const float* __restrict__ sw2, const float* __restrict__ sw3,
                               const float* __restrict__ uw0, const float* __restrict__ uw1,
                               const float* __restrict__ uw2, const float* __restrict__ uw3,
                               short* __restrict__ zb,
                               short* __restrict__ wt0, short* __restrict__ wt1,
                               short* __restrict__ wt2, short* __restrict__ wt3,
                               short* __restrict__ wtu0, short* __restrict__ wtu1,
                               short* __restrict__ wtu2, short* __restrict__ wtu3) {
    __shared__ float tile[32][33];
    int zz = blockIdx.z;
    int tx = threadIdx.x, ty = threadIdx.y;    // 32 x 8
    if (zz == 35) {                            // z [8192][16] -> zb [8192][64] swizzled
        int t = ty * 32 + tx;
        int base = (blockIdx.y * 20 + blockIdx.x) * 256 + t;
        for (int i = base; i < B_SAMPLES * 64; i += 320 * 256) {
            int b = i >> 6, k = i & 63;
            zb[b * 64 + kswz(b, k)] =
                f2bf(k < LATENT_D ? z[(size_t)b * LATENT_D + k] : 0.f);
        }
        return;
    }
    if (zz == 34) {                            // sw0 -> wt0 [512][64]
        if (blockIdx.x >= 16 || blockIdx.y >= 2) return;
        int n0 = blockIdx.x * 32, k0 = blockIdx.y * 32;
        #pragma unroll
        for (int j = 0; j < 32; j += 8) {
            int k = k0 + ty + j;
            tile[ty + j][tx] = (k < LATENT_D) ? sw0[(size_t)k * HID + n0 + tx] : 0.f;
        }
        __syncthreads();
        #pragma unroll
        for (int j = 0; j < 32; j += 8) {
            int n = n0 + ty + j, k = k0 + tx;
            wt0[n * 64 + kswz(n, k)] = f2bf(tile[tx][ty + j]);
        }
        return;
    }
    if (zz == 33) {                            // uw3 -> wtu3 [10][64][512]
        int cls = blockIdx.x >> 1;
        int n0 = (blockIdx.x & 1) * 32, k0 = blockIdx.y * 32;
        const float* s = uw3  + (size_t)cls * HID * STYLE_D;
        short*       d = wtu3 + (size_t)cls * STYLE_D * HID;
        #pragma unroll
        for (int j = 0; j < 32; j += 8)
            tile[ty + j][tx] = s[(size_t)(k0 + ty + j) * STYLE_D + n0 + tx];
        __syncthreads();
        #pragma unroll
        for (int j = 0; j < 32; j += 8) {
            int n = n0 + ty + j, k = k0 + tx;
            d[(size_t)n * HID + kswz(n, k)] = f2bf(tile[tx][ty + j]);
        }
        return;
    }
    if (blockIdx.x >= 16) return;
    const float* s; short* d;
    if      (zz == 0) { s = sw1; d = wt1; }
    else if (zz == 1) { s = sw2; d = wt2; }
    else if (zz == 2) { s = sw3; d = wt3; }
    else if (zz < 13) { size_t o = (size_t)(zz - 3)  * HID * HID; s = uw0 + o; d = wtu0 + o; }
    else if (zz < 23) { size_t o = (size_t)(zz - 13) * HID * HID; s = uw1 + o; d = wtu1 + o; }
    else              { size_t o = (size_t)(zz - 23) * HID * HID; s = uw2 + o; d = wtu2 + o; }
    int n0 = blockIdx.x * 32, k0 = blockIdx.y * 32;
    #pragma unroll
    for (int j = 0; j < 32; j += 8)
        tile[ty + j][tx] = s[(size_t)(k0 + ty + j) * HID + n0 + tx];
    __syncthreads();
    #pragma unroll
    for (int j = 0; j < 32; j += 8) {
        int n = n0 + ty + j, k = k0 + tx;
        d[(size_t)n * HID + kswz(n, k)] = f2bf(tile[tx][ty + j]);
    }
}

// ---------------- one layer, R9-proven 2-phase core ----------------
// MODE 0: bf16 swizzled out, linear rows; 1: scatter rows via rank[];
// 2: same as 0 (sorted domain); 3: fp32 scatter to d_out via order[], N=64.
template <int MODE, int NK>
__device__ __forceinline__ void layer_gemm(
    const short* __restrict__ A, const short* __restrict__ W,
    const float* __restrict__ bs, void* __restrict__ Outv,
    const int row0, const int n0, const int* __restrict__ aux,
    short* As, short* Bs, const int t) {

    constexpr int K = NK * BK;
    const int lane = t & 63, w = t >> 6;
    const int srow = lane >> 3, scol = (lane & 7) * 8;
    const int wr = w >> 1, wc = w & 1;
    const int lrow = lane & 15, lko = lane >> 4;
    const int key = lrow & 7;

    v4f acc[4][2] = {};

    auto stage = [&](int buf, int k0) {
        short* as = As + buf * (BM * BK);
        short* bb = Bs + buf * (BN * BK);
        #pragma unroll
        for (int p = 0; p < 4; ++p) {
            int row = p * 32 + w * 8 + srow;
            gload16(A + (size_t)(row0 + row) * K + k0 + scol, &as[p * 2048 + w * 512]);
        }
        #pragma unroll
        for (int q2 = 0; q2 < 2; ++q2) {
            int row = q2 * 32 + w * 8 + srow;
            gload16(W + (size_t)(n0 + row) * K + k0 + scol, &bb[q2 * 2048 + w * 512]);
        }
    };

    stage(0, 0);
    __syncthreads();
    #pragma unroll
    for (int ks = 0; ks < NK; ++ks) {
        int buf = ks & 1;
        if (ks + 1 < NK) stage(buf ^ 1, (ks + 1) * BK);
        short* as = As + buf * (BM * BK);
        short* bb = Bs + buf * (BN * BK);
        #pragma unroll
        for (int kk = 0; kk < 2; ++kk) {
            int ch = ((kk * 4 + lko) ^ key) << 3;
            v8s af[4], bq[2];
            #pragma unroll
            for (int i = 0; i < 4; ++i)
                af[i] = *(const v8s*)&as[(wr * 64 + i * 16 + lrow) * BK + ch];
            #pragma unroll
            for (int j = 0; j < 2; ++j)
                bq[j] = *(const v8s*)&bb[(wc * 32 + j * 16 + lrow) * BK + ch];
            #pragma unroll
            for (int i = 0; i < 4; ++i)
                #pragma unroll
                for (int j = 0; j < 2; ++j)
                    acc[i][j] = __builtin_amdgcn_mfma_f32_16x16x32_bf16(
                        af[i], bq[j], acc[i][j], 0, 0, 0);
        }
        __syncthreads();   // drains staged loads (aged under MFMA) + read fence
    }

    #pragma unroll
    for (int i = 0; i < 4; ++i)
        #pragma unroll
        for (int j = 0; j < 2; ++j)
            #pragma unroll
            for (int q3 = 0; q3 < 4; ++q3) {
                int rr = wr * 64 + i * 16 + lko * 4 + q3;  // C/D: row=(l>>4)*4+reg
                int c = wc * 32 + j * 16 + lrow;           //      col=l&15
                if (MODE == 3) {
                    int o = aux[row0 + rr];
                    if (o >= 0)
                        ((float*)Outv)[(size_t)o * STYLE_D + n0 + c] = acc[i][j][q3] + bs[n0 + c];
                } else {
                    float v = fmaxf(acc[i][j][q3] + bs[n0 + c], 0.f);
                    int orow = (MODE == 1) ? aux[row0 + rr] : (row0 + rr);
                    ((short*)Outv)[(size_t)orow * HID + cswz(orow & 7, n0, c)] = f2bf(v);
                }
            }
}

// ---------------- fused 8-layer persistent kernel ----------------
// 512 blocks (2/CU, all co-resident). Row-group = 8 blocks sharing a row
// panel (XCD-local by remap). Per-group release/acquire sync between
// row-local layers; ONE global sync after the trunk->sorted scatter.
__global__ __launch_bounds__(256, 2) void mlp8(
    const short* __restrict__ zb,
    const short* __restrict__ wt0, const short* __restrict__ wt1,
    const short* __restrict__ wt2, const short* __restrict__ wt3,
    const short* __restrict__ wtu0, const short* __restrict__ wtu1,
    const short* __restrict__ wtu2, const short* __restrict__ wtu3,
    const float* __restrict__ sb0, const float* __restrict__ sb1,
    const float* __restrict__ sb2, const float* __restrict__ sb3,
    const float* __restrict__ ub0, const float* __restrict__ ub1,
    const float* __restrict__ ub2, const float* __restrict__ ub3,
    short* __restrict__ act0, short* __restrict__ act1, short* __restrict__ act2,
    const int* __restrict__ order, const int* __restrict__ rank,
    const int* __restrict__ tclass, const int* __restrict__ trow0,
    int* __restrict__ cnt, float* __restrict__ out) {

    // XCD-chunk remap (nwg=512: q=64,r=0): each XCD owns 8 full row-groups
    unsigned lin = blockIdx.x;
    unsigned wgid = (lin & 7) * 64 + (lin >> 3);
    const int g = wgid >> 3, np = wgid & 7;    // row-group, n-panel
    const int n0 = np * BN;
    const int t = threadIdx.x;

    __shared__ short As[2 * BM * BK];          // 32 KB
    __shared__ short Bs[2 * BN * BK];          // 16 KB

    const int row0t = g * BM;                  // trunk-domain rows

    // ---- trunk ----
    layer_gemm<0, 1>(zb,   wt0, sb0, act0, row0t, n0, nullptr, As, Bs, t);
    sig(&cnt[0 * 128 + g]);  waitc(&cnt[0 * 128 + g], 8);
    layer_gemm<0, 8>(act0, wt1, sb1, act1, row0t, n0, nullptr, As, Bs, t);
    sig(&cnt[1 * 128 + g]);  waitc(&cnt[1 * 128 + g], 8);
    layer_gemm<0, 8>(act1, wt2, sb2, act0, row0t, n0, nullptr, As, Bs, t);
    sig(&cnt[2 * 128 + g]);  waitc(&cnt[2 * 128 + g], 8);
    layer_gemm<1, 8>(act0, wt3, sb3, act2, row0t, n0, rank,    As, Bs, t);

    // ---- global sync (scatter is all-to-all) ----
    sig(&cnt[6 * 128]);      waitc(&cnt[6 * 128], 512);

    // ---- selected experts: group g owns tile g (+ tile 64+g if g<10) ----
    #pragma unroll 1
    for (int rep = 0; rep < 2; ++rep) {
        if (rep == 1 && g >= MAXT - TRTILES) break;
        const int tile = (rep == 0) ? g : TRTILES + g;
        const int cls = tclass[tile];
        if (cls < 0) continue;                 // whole group agrees
        const int row0 = trow0[tile];
        const size_t wo = (size_t)cls * HID * HID;

        layer_gemm<2, 8>(act2, wtu0 + wo, ub0 + cls * HID, act0, row0, n0, nullptr, As, Bs, t);
        sig(&cnt[3 * 128 + tile]);  waitc(&cnt[3 * 128 + tile], 8);
        layer_gemm<2, 8>(act0, wtu1 + wo, ub1 + cls * HID, act1, row0, n0, nullptr, As, Bs, t);
        sig(&cnt[4 * 128 + tile]);  waitc(&cnt[4 * 128 + tile], 8);
        layer_gemm<2, 8>(act1, wtu2 + wo, ub2 + cls * HID, act0, row0, n0, nullptr, As, Bs, t);
        sig(&cnt[5 * 128 + tile]);  waitc(&cnt[5 * 128 + tile], 8);
        if (np == 0)                           // final N=64 layer: one n-panel
            layer_gemm<3, 8>(act0, wtu3 + (size_t)cls * STYLE_D * HID,
                             ub3 + cls * STYLE_D, out, row0, 0, order, As, Bs, t);
    }
}

// ---------------- launcher ----------------
extern "C" void kernel_launch(void* const* d_in, const int* in_sizes, int n_in,
                              void* d_out, int out_size, void* d_ws, size_t ws_size,
                              hipStream_t stream) {
    const float* z   = (const float*)d_in[0];
    const int*   y   = (const int*)d_in[1];
    const float* sw0 = (const float*)d_in[2];
    const float* sb0 = (const float*)d_in[3];
    const float* sw1 = (const float*)d_in[4];
    const float* sb1 = (const float*)d_in[5];
    const float* sw2 = (const float*)d_in[6];
    const float* sb2 = (const float*)d_in[7];
    const float* sw3 = (const float*)d_in[8];
    const float* sb3 = (const float*)d_in[9];
    const float* uw0 = (const float*)d_in[10];
    const float* ub0 = (const float*)d_in[11];
    const float* uw1 = (const float*)d_in[12];
    const float* ub1 = (const float*)d_in[13];
    const float* uw2 = (const float*)d_in[14];
    const float* ub2 = (const float*)d_in[15];
    const float* uw3 = (const float*)d_in[16];
    const float* ub3 = (const float*)d_in[17];

    char* p = (char*)d_ws;
    auto alloc = [&](size_t bytes) -> char* {
        char* r = p; p += (bytes + 255) & ~(size_t)255; return r;
    };
    int*   cnt    = (int*)alloc(NCNT * 4);
    int*   tclass = (int*)alloc(MAXT * 4);
    int*   trow0  = (int*)alloc(MAXT * 4);
    int*   order  = (int*)alloc(MAXROWS * 4);
    int*   rank   = (int*)alloc(B_SAMPLES * 4);
    short* zb     = (short*)alloc((size_t)B_SAMPLES * 64 * 2);
    short* wt0    = (short*)alloc((size_t)HID * 64 * 2);
    short* wt1    = (short*)alloc((size_t)HID * HID * 2);
    short* wt2    = (short*)alloc((size_t)HID * HID * 2);
    short* wt3    = (short*)alloc((size_t)HID * HID * 2);
    short* wtu0   = (short*)alloc((size_t)NCLS * HID * HID * 2);
    short* wtu1   = (short*)alloc((size_t)NCLS * HID * HID * 2);
    short* wtu2   = (short*)alloc((size_t)NCLS * HID * HID * 2);
    short* wtu3   = (short*)alloc((size_t)NCLS * STYLE_D * HID * 2);
    short* act0   = (short*)alloc((size_t)MAXROWS * HID * 2);
    short* act1   = (short*)alloc((size_t)MAXROWS * HID * 2);
    short* act2   = (short*)alloc((size_t)MAXROWS * HID * 2);

    build_groups<<<1, 1024, 0, stream>>>(y, tclass, trow0, order, rank, cnt);
    dim3 tb(32, 8);
    transpose_mega<<<dim3(20, 16, 36), tb, 0, stream>>>(
        z, sw0, sw1, sw2, sw3, uw0, uw1, uw2, uw3,
        zb, wt0, wt1, wt2, wt3, wtu0, wtu1, wtu2, wtu3);

    mlp8<<<512, 256, 0, stream>>>(
        zb, wt0, wt1, wt2, wt3, wtu0, wtu1, wtu2, wtu3,
        sb0, sb1, sb2, sb3, ub0, ub1, ub2, ub3,
        act0, act1, act2, order, rank, tclass, trow0,
        cnt, (float*)d_out);
}

// Round 13
// 125.775 us; speedup vs baseline: 4.3502x; 4.3502x over previous
//
#include <hip/hip_runtime.h>

// ---------------- problem constants ----------------
#define B_SAMPLES 8192
#define HID       512
#define NCLS      10
#define STYLE_D   64
#define LATENT_D  16

#define BM 128
#define BN 64
#define BK 64
#define MAXT    (B_SAMPLES/BM + NCLS)     // 74 worst-case expert row tiles
#define MAXROWS (B_SAMPLES + NCLS*BM)     // 9472 padded sorted rows

typedef short v8s __attribute__((ext_vector_type(8)));
typedef float v4f __attribute__((ext_vector_type(4)));

__device__ __forceinline__ short f2bf(float f) {
    union { float f; unsigned u; } x; x.f = f;
    unsigned r = x.u + 0x7fffu + ((x.u >> 16) & 1u);   // RNE; inputs finite
    return (short)(r >> 16);
}

__device__ __forceinline__ void gload16(const short* g, short* l) {
    __builtin_amdgcn_global_load_lds(
        (const __attribute__((address_space(1))) void*)g,
        (__attribute__((address_space(3))) void*)l, 16, 0, 0);
}

// global pre-swizzle: within each 64-elem slice of a row, XOR the 16B chunk
// index with (row&7). Writers store swizzled; global_load_lds copies rows
// linearly; fragment ds_reads XOR the same key (rule #21: both sides).
__device__ __forceinline__ int kswz(int row, int k) {
    return (k & ~63) + ((((k >> 3) & 7) ^ (row & 7)) << 3) + (k & 7);
}
__device__ __forceinline__ int cswz(int key, int n0, int c) {
    return n0 + ((((c >> 3) ^ key) & 7) << 3) + (c & 7);
}

// ---------------- grouping (one block) ----------------
__global__ void build_groups(const int* __restrict__ y, int* __restrict__ tclass,
                             int* __restrict__ trow0, int* __restrict__ order,
                             int* __restrict__ rank) {
    __shared__ int cnt[NCLS], cur[NCLS];
    int t = threadIdx.x;                       // 1024 threads
    if (t < NCLS) cnt[t] = 0;
    __syncthreads();
    for (int b = t; b < B_SAMPLES; b += 1024) atomicAdd(&cnt[y[b]], 1);
    __syncthreads();
    if (t == 0) {
        int off = 0, tt = 0;
        for (int c = 0; c < NCLS; ++c) {
            cur[c] = off;
            int nt = (cnt[c] + BM - 1) / BM;
            for (int j = 0; j < nt; ++j) { tclass[tt] = c; trow0[tt] = off + j * BM; ++tt; }
            off += nt * BM;
        }
        for (int u = tt; u < MAXT; ++u) { tclass[u] = -1; trow0[u] = 0; }
    }
    __syncthreads();
    for (int i = t; i < MAXROWS; i += 1024) order[i] = -1;
    __syncthreads();
    for (int b = t; b < B_SAMPLES; b += 1024) {
        int c = y[b];
        int p = atomicAdd(&cur[c], 1);
        order[p] = b;
        rank[b] = p;
    }
}

// mega transpose -> bf16 [n][k], PRE-SWIZZLED rows. grid (20,16,36).
// zz<33 (bx<16): 512x512 slices; zz==33: uw3; zz==34: sw0->wt0; zz==35: z->zb
__global__ void transpose_mega(const float* __restrict__ z,
                               const float* __restrict__ sw0, const float* __restrict__ sw1,
                               const float* __restrict__ sw2, const float* __restrict__ sw3,
                               const float* __restrict__ uw0, const float* __restrict__ uw1,
                               const float* __restrict__ uw2, const float* __restrict__ uw3,
                               short* __restrict__ zb,
                               short* __restrict__ wt0, short* __restrict__ wt1,
                               short* __restrict__ wt2, short* __restrict__ wt3,
                               short* __restrict__ wtu0, short* __restrict__ wtu1,
                               short* __restrict__ wtu2, short* __restrict__ wtu3) {
    __shared__ float tile[32][33];
    int zz = blockIdx.z;
    int tx = threadIdx.x, ty = threadIdx.y;    // 32 x 8
    if (zz == 35) {                            // z [8192][16] -> zb [8192][64] swizzled
        int t = ty * 32 + tx;
        int base = (blockIdx.y * 20 + blockIdx.x) * 256 + t;
        for (int i = base; i < B_SAMPLES * 64; i += 320 * 256) {
            int b = i >> 6, k = i & 63;
            zb[b * 64 + kswz(b, k)] =
                f2bf(k < LATENT_D ? z[(size_t)b * LATENT_D + k] : 0.f);
        }
        return;
    }
    if (zz == 34) {                            // sw0 -> wt0 [512][64]
        if (blockIdx.x >= 16 || blockIdx.y >= 2) return;
        int n0 = blockIdx.x * 32, k0 = blockIdx.y * 32;
        #pragma unroll
        for (int j = 0; j < 32; j += 8) {
            int k = k0 + ty + j;
            tile[ty + j][tx] = (k < LATENT_D) ? sw0[(size_t)k * HID + n0 + tx] : 0.f;
        }
        __syncthreads();
        #pragma unroll
        for (int j = 0; j < 32; j += 8) {
            int n = n0 + ty + j, k = k0 + tx;
            wt0[n * 64 + kswz(n, k)] = f2bf(tile[tx][ty + j]);
        }
        return;
    }
    if (zz == 33) {                            // uw3 -> wtu3 [10][64][512]
        int cls = blockIdx.x >> 1;
        int n0 = (blockIdx.x & 1) * 32, k0 = blockIdx.y * 32;
        const float* s = uw3  + (size_t)cls * HID * STYLE_D;
        short*       d = wtu3 + (size_t)cls * STYLE_D * HID;
        #pragma unroll
        for (int j = 0; j < 32; j += 8)
            tile[ty + j][tx] = s[(size_t)(k0 + ty + j) * STYLE_D + n0 + tx];
        __syncthreads();
        #pragma unroll
        for (int j = 0; j < 32; j += 8) {
            int n = n0 + ty + j, k = k0 + tx;
            d[(size_t)n * HID + kswz(n, k)] = f2bf(tile[tx][ty + j]);
        }
        return;
    }
    if (blockIdx.x >= 16) return;
    const float* s; short* d;
    if      (zz == 0) { s = sw1; d = wt1; }
    else if (zz == 1) { s = sw2; d = wt2; }
    else if (zz == 2) { s = sw3; d = wt3; }
    else if (zz < 13) { size_t o = (size_t)(zz - 3)  * HID * HID; s = uw0 + o; d = wtu0 + o; }
    else if (zz < 23) { size_t o = (size_t)(zz - 13) * HID * HID; s = uw1 + o; d = wtu1 + o; }
    else              { size_t o = (size_t)(zz - 23) * HID * HID; s = uw2 + o; d = wtu2 + o; }
    int n0 = blockIdx.x * 32, k0 = blockIdx.y * 32;
    #pragma unroll
    for (int j = 0; j < 32; j += 8)
        tile[ty + j][tx] = s[(size_t)(k0 + ty + j) * HID + n0 + tx];
    __syncthreads();
    #pragma unroll
    for (int j = 0; j < 32; j += 8) {
        int n = n0 + ty + j, k = k0 + tx;
        d[(size_t)n * HID + kswz(n, k)] = f2bf(tile[tx][ty + j]);
    }
}

// ---- core GEMM: 128x64, 3-buffer 2-deep pipeline, clobber-free waits ----
// Per iter: {vmcnt(6); SB0; s_barrier(builtin, no drain); SB0; stage(ks+2);
//            setprio(1); ds_read frags + 16 MFMA; setprio(0)}.
// vmcnt(6): stage(ks) done, stage(ks+1) still in flight (T4: never drain
// mid-loop). WAR: stage(ks+2) overwrites buf[ks-1], whose ds_reads completed
// before every wave's barrier(ks) arrival (lgkm wait precedes MFMA issue).
// MODE 0: trunk linear; 1: trunk L3 scatter-to-rank; 2: expert mid;
// 3: expert last (fp32 scatter to d_out). NK = K/BK (compile-time).
template <int MODE, int NK>
__global__ __launch_bounds__(256, 2) void gemmp(
    const short* __restrict__ A, const short* __restrict__ WT,
    const float* __restrict__ bias, void* __restrict__ Outv,
    const int N, const long wStride, const int biasN,
    const int* __restrict__ aux, const int* __restrict__ tclass,
    const int* __restrict__ trow0) {

    constexpr int K = NK * BK;
    // T1: bijective XCD-chunk remap (m204): row-panels stay XCD-stable
    const unsigned gx = gridDim.x;
    const unsigned nwg = gx * gridDim.y;
    unsigned lin = blockIdx.x + gx * blockIdx.y;
    {
        unsigned q = nwg >> 3, r = nwg & 7, xcd = lin & 7, idx = lin >> 3;
        lin = (xcd < r ? xcd * (q + 1) : r * (q + 1) + (xcd - r) * q) + idx;
    }
    const unsigned bx = lin % gx, by = lin / gx;

    int tile = by, cls = 0, row0;
    if (MODE <= 1) {
        row0 = tile * BM;
    } else {
        cls = tclass[tile];
        if (cls < 0) return;               // uniform block exit
        row0 = trow0[tile];
    }
    const int n0 = bx * BN;
    const short* wt = WT + (size_t)cls * wStride;
    const float* bs = bias + (size_t)cls * biasN;

    __shared__ short As[3][BM * BK];       // 3 x 16 KB
    __shared__ short Bs[3][BN * BK];       // 3 x  8 KB  -> 72 KB (2 blocks/CU)

    const int t = threadIdx.x, lane = t & 63, w = t >> 6;
    const int srow = lane >> 3, scol = (lane & 7) * 8;   // 8 lanes x 16B per row
    const int wr = w >> 1, wc = w & 1;
    const int lrow = lane & 15, lko = lane >> 4;
    const int key = lrow & 7;

    v4f acc[4][2] = {};

    auto stage = [&](int buf, int k0) {    // 6 VMEM instrs per wave
        #pragma unroll
        for (int p = 0; p < 4; ++p) {
            int row = p * 32 + w * 8 + srow;
            gload16(A + (size_t)(row0 + row) * K + k0 + scol, &As[buf][p * 2048 + w * 512]);
        }
        #pragma unroll
        for (int q2 = 0; q2 < 2; ++q2) {
            int row = q2 * 32 + w * 8 + srow;
            gload16(wt + (size_t)(n0 + row) * K + k0 + scol, &Bs[buf][q2 * 2048 + w * 512]);
        }
    };

    stage(0, 0);
    if (NK > 1) stage(1, BK);

    #pragma unroll
    for (int ks = 0; ks < NK; ++ks) {
        const int buf = ks % 3;
        // wait own stage-ks loads; NO memory clobber (else compiler pre-drains)
        if (ks < NK - 1) asm volatile("s_waitcnt vmcnt(6)");
        else             asm volatile("s_waitcnt vmcnt(0)");
        __builtin_amdgcn_sched_barrier(0);
        __builtin_amdgcn_s_barrier();      // no fence: counters NOT drained
        __builtin_amdgcn_sched_barrier(0);
        if (ks + 2 < NK) stage((ks + 2) % 3, (ks + 2) * BK);

        __builtin_amdgcn_s_setprio(1);
        #pragma unroll
        for (int kk = 0; kk < 2; ++kk) {
            int ch = ((kk * 4 + lko) ^ key) << 3;
            v8s af[4], bq[2];
            #pragma unroll
            for (int i = 0; i < 4; ++i)
                af[i] = *(const v8s*)&As[buf][(wr * 64 + i * 16 + lrow) * BK + ch];
            #pragma unroll
            for (int j = 0; j < 2; ++j)
                bq[j] = *(const v8s*)&Bs[buf][(wc * 32 + j * 16 + lrow) * BK + ch];
            #pragma unroll
            for (int i = 0; i < 4; ++i)
                #pragma unroll
                for (int j = 0; j < 2; ++j)
                    acc[i][j] = __builtin_amdgcn_mfma_f32_16x16x32_bf16(
                        af[i], bq[j], acc[i][j], 0, 0, 0);
        }
        __builtin_amdgcn_s_setprio(0);
        __builtin_amdgcn_sched_barrier(0);
    }

    // ---- epilogue ----
    #pragma unroll
    for (int i = 0; i < 4; ++i)
        #pragma unroll
        for (int j = 0; j < 2; ++j)
            #pragma unroll
            for (int q3 = 0; q3 < 4; ++q3) {
                int rr = wr * 64 + i * 16 + lko * 4 + q3;  // C/D: row=(l>>4)*4+reg
                int c = wc * 32 + j * 16 + lrow;           //      col=l&15
                if (MODE == 3) {
                    int o = aux[row0 + rr];                // order (pos -> sample)
                    if (o >= 0)
                        ((float*)Outv)[(size_t)o * STYLE_D + n0 + c] = acc[i][j][q3] + bs[n0 + c];
                } else {
                    float v = fmaxf(acc[i][j][q3] + bs[n0 + c], 0.f);
                    int orow = (MODE == 1) ? aux[row0 + rr] : (row0 + rr);
                    ((short*)Outv)[(size_t)orow * N + cswz(orow & 7, n0, c)] = f2bf(v);
                }
            }
}

// ---------------- launcher ----------------
extern "C" void kernel_launch(void* const* d_in, const int* in_sizes, int n_in,
                              void* d_out, int out_size, void* d_ws, size_t ws_size,
                              hipStream_t stream) {
    const float* z   = (const float*)d_in[0];
    const int*   y   = (const int*)d_in[1];
    const float* sw0 = (const float*)d_in[2];
    const float* sb0 = (const float*)d_in[3];
    const float* sw1 = (const float*)d_in[4];
    const float* sb1 = (const float*)d_in[5];
    const float* sw2 = (const float*)d_in[6];
    const float* sb2 = (const float*)d_in[7];
    const float* sw3 = (const float*)d_in[8];
    const float* sb3 = (const float*)d_in[9];
    const float* uw0 = (const float*)d_in[10];
    const float* ub0 = (const float*)d_in[11];
    const float* uw1 = (const float*)d_in[12];
    const float* ub1 = (const float*)d_in[13];
    const float* uw2 = (const float*)d_in[14];
    const float* ub2 = (const float*)d_in[15];
    const float* uw3 = (const float*)d_in[16];
    const float* ub3 = (const float*)d_in[17];

    char* p = (char*)d_ws;
    auto alloc = [&](size_t bytes) -> char* {
        char* r = p; p += (bytes + 255) & ~(size_t)255; return r;
    };
    int*   tclass = (int*)alloc(MAXT * 4);
    int*   trow0  = (int*)alloc(MAXT * 4);
    int*   order  = (int*)alloc(MAXROWS * 4);
    int*   rank   = (int*)alloc(B_SAMPLES * 4);
    short* zb     = (short*)alloc((size_t)B_SAMPLES * 64 * 2);
    short* wt0    = (short*)alloc((size_t)HID * 64 * 2);
    short* wt1    = (short*)alloc((size_t)HID * HID * 2);
    short* wt2    = (short*)alloc((size_t)HID * HID * 2);
    short* wt3    = (short*)alloc((size_t)HID * HID * 2);
    short* wtu0   = (short*)alloc((size_t)NCLS * HID * HID * 2);
    short* wtu1   = (short*)alloc((size_t)NCLS * HID * HID * 2);
    short* wtu2   = (short*)alloc((size_t)NCLS * HID * HID * 2);
    short* wtu3   = (short*)alloc((size_t)NCLS * STYLE_D * HID * 2);
    short* act0   = (short*)alloc((size_t)MAXROWS * HID * 2);
    short* act1   = (short*)alloc((size_t)MAXROWS * HID * 2);
    short* act2   = (short*)alloc((size_t)MAXROWS * HID * 2);     // sorted trunk out

    build_groups<<<1, 1024, 0, stream>>>(y, tclass, trow0, order, rank);
    dim3 tb(32, 8);
    transpose_mega<<<dim3(20, 16, 36), tb, 0, stream>>>(
        z, sw0, sw1, sw2, sw3, uw0, uw1, uw2, uw3,
        zb, wt0, wt1, wt2, wt3, wtu0, wtu1, wtu2, wtu3);

    // trunk
    gemmp<0, 1><<<dim3(HID / BN, B_SAMPLES / BM), 256, 0, stream>>>(
        zb, wt0, sb0, act0, HID, 0, 0, nullptr, nullptr, nullptr);
    gemmp<0, 8><<<dim3(HID / BN, B_SAMPLES / BM), 256, 0, stream>>>(
        act0, wt1, sb1, act1, HID, 0, 0, nullptr, nullptr, nullptr);
    gemmp<0, 8><<<dim3(HID / BN, B_SAMPLES / BM), 256, 0, stream>>>(
        act1, wt2, sb2, act0, HID, 0, 0, nullptr, nullptr, nullptr);
    gemmp<1, 8><<<dim3(HID / BN, B_SAMPLES / BM), 256, 0, stream>>>(
        act0, wt3, sb3, act2, HID, 0, 0, rank, nullptr, nullptr);

    // selected experts (class-grouped, sorted-linear rows)
    gemmp<2, 8><<<dim3(HID / BN, MAXT), 256, 0, stream>>>(
        act2, wtu0, ub0, act0, HID, (long)HID * HID, HID, nullptr, tclass, trow0);
    gemmp<2, 8><<<dim3(HID / BN, MAXT), 256, 0, stream>>>(
        act0, wtu1, ub1, act1, HID, (long)HID * HID, HID, nullptr, tclass, trow0);
    gemmp<2, 8><<<dim3(HID / BN, MAXT), 256, 0, stream>>>(
        act1, wtu2, ub2, act0, HID, (long)HID * HID, HID, nullptr, tclass, trow0);
    gemmp<3, 8><<<dim3(1, MAXT), 256, 0, stream>>>(
        act0, wtu3, ub3, d_out, HID, (long)STYLE_D * HID, STYLE_D, order, tclass, trow0);
}

// Round 14
// 117.656 us; speedup vs baseline: 4.6504x; 1.0690x over previous
//
#include <hip/hip_runtime.h>

// ---------------- problem constants ----------------
#define B_SAMPLES 8192
#define HID       512
#define NCLS      10
#define STYLE_D   64
#define LATENT_D  16

#define BM 128
#define BN 64
#define BK 64
#define MAXT    (B_SAMPLES/BM + NCLS)     // 74 worst-case expert row tiles
#define MAXROWS (B_SAMPLES + NCLS*BM)     // 9472 padded sorted rows

typedef short v8s __attribute__((ext_vector_type(8)));
typedef float v4f __attribute__((ext_vector_type(4)));

__device__ __forceinline__ short f2bf(float f) {
    union { float f; unsigned u; } x; x.f = f;
    unsigned r = x.u + 0x7fffu + ((x.u >> 16) & 1u);   // RNE; inputs finite
    return (short)(r >> 16);
}

__device__ __forceinline__ void gload16(const short* g, short* l) {
    __builtin_amdgcn_global_load_lds(
        (const __attribute__((address_space(1))) void*)g,
        (__attribute__((address_space(3))) void*)l, 16, 0, 0);
}

// global pre-swizzle: within each 64-elem slice of a row, XOR the 16B chunk
// index with (row&7). Writers store swizzled; global_load_lds copies rows
// linearly; fragment ds_reads XOR the same key (rule #21: both sides).
__device__ __forceinline__ int kswz(int row, int k) {
    return (k & ~63) + ((((k >> 3) & 7) ^ (row & 7)) << 3) + (k & 7);
}
__device__ __forceinline__ int cswz(int key, int n0, int c) {
    return n0 + ((((c >> 3) ^ key) & 7) << 3) + (c & 7);
}

// mega prep kernel. grid (20,16,37), 256 threads (32x8).
// zz<33 (bx<16): 512x512 transposes; zz==33: uw3; zz==34: sw0->wt0;
// zz==35: z->zb; zz==36 (one block): class grouping.
__global__ void prep_all(const float* __restrict__ z, const int* __restrict__ y,
                         const float* __restrict__ sw0, const float* __restrict__ sw1,
                         const float* __restrict__ sw2, const float* __restrict__ sw3,
                         const float* __restrict__ uw0, const float* __restrict__ uw1,
                         const float* __restrict__ uw2, const float* __restrict__ uw3,
                         short* __restrict__ zb,
                         short* __restrict__ wt0, short* __restrict__ wt1,
                         short* __restrict__ wt2, short* __restrict__ wt3,
                         short* __restrict__ wtu0, short* __restrict__ wtu1,
                         short* __restrict__ wtu2, short* __restrict__ wtu3,
                         int* __restrict__ tclass, int* __restrict__ trow0,
                         int* __restrict__ order, int* __restrict__ rank) {
    __shared__ float tile[32][33];
    int zz = blockIdx.z;
    int tx = threadIdx.x, ty = threadIdx.y;    // 32 x 8
    int t = ty * 32 + tx;                      // 0..255
    if (zz == 36) {                            // class grouping (one block)
        if (blockIdx.x || blockIdx.y) return;
        __shared__ int cnt[NCLS], cur[NCLS];
        if (t < NCLS) cnt[t] = 0;
        __syncthreads();
        for (int b = t; b < B_SAMPLES; b += 256) atomicAdd(&cnt[y[b]], 1);
        __syncthreads();
        if (t == 0) {
            int off = 0, tt = 0;
            for (int c = 0; c < NCLS; ++c) {
                cur[c] = off;
                int nt = (cnt[c] + BM - 1) / BM;
                for (int j = 0; j < nt; ++j) { tclass[tt] = c; trow0[tt] = off + j * BM; ++tt; }
                off += nt * BM;
            }
            for (int u = tt; u < MAXT; ++u) { tclass[u] = -1; trow0[u] = 0; }
        }
        __syncthreads();
        for (int i = t; i < MAXROWS; i += 256) order[i] = -1;
        __syncthreads();
        for (int b = t; b < B_SAMPLES; b += 256) {
            int c = y[b];
            int p = atomicAdd(&cur[c], 1);
            order[p] = b;
            rank[b] = p;
        }
        return;
    }
    if (zz == 35) {                            // z [8192][16] -> zb [8192][64] swizzled
        int base = (blockIdx.y * 20 + blockIdx.x) * 256 + t;
        for (int i = base; i < B_SAMPLES * 64; i += 320 * 256) {
            int b = i >> 6, k = i & 63;
            zb[b * 64 + kswz(b, k)] =
                f2bf(k < LATENT_D ? z[(size_t)b * LATENT_D + k] : 0.f);
        }
        return;
    }
    if (zz == 34) {                            // sw0 -> wt0 [512][64]
        if (blockIdx.x >= 16 || blockIdx.y >= 2) return;
        int n0 = blockIdx.x * 32, k0 = blockIdx.y * 32;
        #pragma unroll
        for (int j = 0; j < 32; j += 8) {
            int k = k0 + ty + j;
            tile[ty + j][tx] = (k < LATENT_D) ? sw0[(size_t)k * HID + n0 + tx] : 0.f;
        }
        __syncthreads();
        #pragma unroll
        for (int j = 0; j < 32; j += 8) {
            int n = n0 + ty + j, k = k0 + tx;
            wt0[n * 64 + kswz(n, k)] = f2bf(tile[tx][ty + j]);
        }
        return;
    }
    if (zz == 33) {                            // uw3 -> wtu3 [10][64][512]
        int cls = blockIdx.x >> 1;
        if (cls >= NCLS) return;
        int n0 = (blockIdx.x & 1) * 32, k0 = blockIdx.y * 32;
        const float* s = uw3  + (size_t)cls * HID * STYLE_D;
        short*       d = wtu3 + (size_t)cls * STYLE_D * HID;
        #pragma unroll
        for (int j = 0; j < 32; j += 8)
            tile[ty + j][tx] = s[(size_t)(k0 + ty + j) * STYLE_D + n0 + tx];
        __syncthreads();
        #pragma unroll
        for (int j = 0; j < 32; j += 8) {
            int n = n0 + ty + j, k = k0 + tx;
            d[(size_t)n * HID + kswz(n, k)] = f2bf(tile[tx][ty + j]);
        }
        return;
    }
    if (blockIdx.x >= 16) return;
    const float* s; short* d;
    if      (zz == 0) { s = sw1; d = wt1; }
    else if (zz == 1) { s = sw2; d = wt2; }
    else if (zz == 2) { s = sw3; d = wt3; }
    else if (zz < 13) { size_t o = (size_t)(zz - 3)  * HID * HID; s = uw0 + o; d = wtu0 + o; }
    else if (zz < 23) { size_t o = (size_t)(zz - 13) * HID * HID; s = uw1 + o; d = wtu1 + o; }
    else              { size_t o = (size_t)(zz - 23) * HID * HID; s = uw2 + o; d = wtu2 + o; }
    int n0 = blockIdx.x * 32, k0 = blockIdx.y * 32;
    #pragma unroll
    for (int j = 0; j < 32; j += 8)
        tile[ty + j][tx] = s[(size_t)(k0 + ty + j) * HID + n0 + tx];
    __syncthreads();
    #pragma unroll
    for (int j = 0; j < 32; j += 8) {
        int n = n0 + ty + j, k = k0 + tx;
        d[(size_t)n * HID + kswz(n, k)] = f2bf(tile[tx][ty + j]);
    }
}

// ---- core GEMM: 128x64 tile, BK=64, R9-proven 2-phase loop, 8 WAVES ----
// 512 thr = 8 waves (4 row x 2 col), 2x2 16x16 frags/wave. 2 blocks/CU ->
// 16 waves/CU (4/SIMD) for latency hiding (R9 had only 2/SIMD).
// MODE 0: trunk linear; 1: trunk L3 scatter-to-rank; 2: expert mid;
// 3: expert last (fp32 scatter to d_out). NK = K/BK (compile-time).
template <int MODE, int NK>
__global__ __launch_bounds__(512, 4) void gemm8w(
    const short* __restrict__ A, const short* __restrict__ WT,
    const float* __restrict__ bias, void* __restrict__ Outv,
    const int N, const long wStride, const int biasN,
    const int* __restrict__ aux, const int* __restrict__ tclass,
    const int* __restrict__ trow0) {

    constexpr int K = NK * BK;
    // T1: bijective XCD-chunk remap (m204): row-panels stay XCD-stable
    const unsigned gx = gridDim.x;
    const unsigned nwg = gx * gridDim.y;
    unsigned lin = blockIdx.x + gx * blockIdx.y;
    {
        unsigned q = nwg >> 3, r = nwg & 7, xcd = lin & 7, idx = lin >> 3;
        lin = (xcd < r ? xcd * (q + 1) : r * (q + 1) + (xcd - r) * q) + idx;
    }
    const unsigned bx = lin % gx, by = lin / gx;

    int tile = by, cls = 0, row0;
    if (MODE <= 1) {
        row0 = tile * BM;
    } else {
        cls = tclass[tile];
        if (cls < 0) return;               // uniform block exit
        row0 = trow0[tile];
    }
    const int n0 = bx * BN;
    const short* wt = WT + (size_t)cls * wStride;
    const float* bs = bias + (size_t)cls * biasN;

    __shared__ short As[2][BM * BK];       // 2 x 16 KB
    __shared__ short Bs[2][BN * BK];       // 2 x  8 KB  -> 48 KB (2 blocks/CU)

    const int t = threadIdx.x, lane = t & 63, w = t >> 6;      // w: 0..7
    const int srow = lane >> 3, scol = (lane & 7) * 8;   // 8 lanes x 16B per row
    const int wr = w >> 1, wc = w & 1;                   // 4 x 2 wave grid
    const int lrow = lane & 15, lko = lane >> 4;
    const int key = lrow & 7;

    v4f acc[2][2] = {};

    auto stage = [&](int buf, int k0) {    // 3 VMEM instrs per wave
        #pragma unroll
        for (int p = 0; p < 2; ++p) {
            int row = w * 16 + p * 8 + srow;
            gload16(A + (size_t)(row0 + row) * K + k0 + scol,
                    &As[buf][(w * 16 + p * 8) * 64]);
        }
        int rowb = w * 8 + srow;
        gload16(wt + (size_t)(n0 + rowb) * K + k0 + scol,
                &Bs[buf][(w * 8) * 64]);
    };

    stage(0, 0);
    __syncthreads();
    #pragma unroll
    for (int ks = 0; ks < NK; ++ks) {
        int buf = ks & 1;
        if (ks + 1 < NK) stage(buf ^ 1, (ks + 1) * BK);   // prefetch next tile

        #pragma unroll
        for (int kk = 0; kk < 2; ++kk) {
            int ch = ((kk * 4 + lko) ^ key) << 3;
            v8s af[2], bq[2];
            #pragma unroll
            for (int i = 0; i < 2; ++i)
                af[i] = *(const v8s*)&As[buf][(wr * 32 + i * 16 + lrow) * BK + ch];
            #pragma unroll
            for (int j = 0; j < 2; ++j)
                bq[j] = *(const v8s*)&Bs[buf][(wc * 32 + j * 16 + lrow) * BK + ch];
            #pragma unroll
            for (int i = 0; i < 2; ++i)
                #pragma unroll
                for (int j = 0; j < 2; ++j)
                    acc[i][j] = __builtin_amdgcn_mfma_f32_16x16x32_bf16(
                        af[i], bq[j], acc[i][j], 0, 0, 0);
        }
        __syncthreads();   // drains staged loads (aged under MFMA) + read fence
    }

    // ---- epilogue ----
    #pragma unroll
    for (int i = 0; i < 2; ++i)
        #pragma unroll
        for (int j = 0; j < 2; ++j)
            #pragma unroll
            for (int q3 = 0; q3 < 4; ++q3) {
                int rr = wr * 32 + i * 16 + lko * 4 + q3;  // C/D: row=(l>>4)*4+reg
                int c = wc * 32 + j * 16 + lrow;           //      col=l&15
                if (MODE == 3) {
                    int o = aux[row0 + rr];                // order (pos -> sample)
                    if (o >= 0)
                        ((float*)Outv)[(size_t)o * STYLE_D + n0 + c] = acc[i][j][q3] + bs[n0 + c];
                } else {
                    float v = fmaxf(acc[i][j][q3] + bs[n0 + c], 0.f);
                    int orow = (MODE == 1) ? aux[row0 + rr] : (row0 + rr);
                    ((short*)Outv)[(size_t)orow * N + cswz(orow & 7, n0, c)] = f2bf(v);
                }
            }
}

// ---------------- launcher ----------------
extern "C" void kernel_launch(void* const* d_in, const int* in_sizes, int n_in,
                              void* d_out, int out_size, void* d_ws, size_t ws_size,
                              hipStream_t stream) {
    const float* z   = (const float*)d_in[0];
    const int*   y   = (const int*)d_in[1];
    const float* sw0 = (const float*)d_in[2];
    const float* sb0 = (const float*)d_in[3];
    const float* sw1 = (const float*)d_in[4];
    const float* sb1 = (const float*)d_in[5];
    const float* sw2 = (const float*)d_in[6];
    const float* sb2 = (const float*)d_in[7];
    const float* sw3 = (const float*)d_in[8];
    const float* sb3 = (const float*)d_in[9];
    const float* uw0 = (const float*)d_in[10];
    const float* ub0 = (const float*)d_in[11];
    const float* uw1 = (const float*)d_in[12];
    const float* ub1 = (const float*)d_in[13];
    const float* uw2 = (const float*)d_in[14];
    const float* ub2 = (const float*)d_in[15];
    const float* uw3 = (const float*)d_in[16];
    const float* ub3 = (const float*)d_in[17];

    char* p = (char*)d_ws;
    auto alloc = [&](size_t bytes) -> char* {
        char* r = p; p += (bytes + 255) & ~(size_t)255; return r;
    };
    int*   tclass = (int*)alloc(MAXT * 4);
    int*   trow0  = (int*)alloc(MAXT * 4);
    int*   order  = (int*)alloc(MAXROWS * 4);
    int*   rank   = (int*)alloc(B_SAMPLES * 4);
    short* zb     = (short*)alloc((size_t)B_SAMPLES * 64 * 2);
    short* wt0    = (short*)alloc((size_t)HID * 64 * 2);
    short* wt1    = (short*)alloc((size_t)HID * HID * 2);
    short* wt2    = (short*)alloc((size_t)HID * HID * 2);
    short* wt3    = (short*)alloc((size_t)HID * HID * 2);
    short* wtu0   = (short*)alloc((size_t)NCLS * HID * HID * 2);
    short* wtu1   = (short*)alloc((size_t)NCLS * HID * HID * 2);
    short* wtu2   = (short*)alloc((size_t)NCLS * HID * HID * 2);
    short* wtu3   = (short*)alloc((size_t)NCLS * STYLE_D * HID * 2);
    short* act0   = (short*)alloc((size_t)MAXROWS * HID * 2);
    short* act1   = (short*)alloc((size_t)MAXROWS * HID * 2);
    short* act2   = (short*)alloc((size_t)MAXROWS * HID * 2);     // sorted trunk out

    dim3 tb(32, 8);
    prep_all<<<dim3(20, 16, 37), tb, 0, stream>>>(
        z, y, sw0, sw1, sw2, sw3, uw0, uw1, uw2, uw3,
        zb, wt0, wt1, wt2, wt3, wtu0, wtu1, wtu2, wtu3,
        tclass, trow0, order, rank);

    // trunk
    gemm8w<0, 1><<<dim3(HID / BN, B_SAMPLES / BM), 512, 0, stream>>>(
        zb, wt0, sb0, act0, HID, 0, 0, nullptr, nullptr, nullptr);
    gemm8w<0, 8><<<dim3(HID / BN, B_SAMPLES / BM), 512, 0, stream>>>(
        act0, wt1, sb1, act1, HID, 0, 0, nullptr, nullptr, nullptr);
    gemm8w<0, 8><<<dim3(HID / BN, B_SAMPLES / BM), 512, 0, stream>>>(
        act1, wt2, sb2, act0, HID, 0, 0, nullptr, nullptr, nullptr);
    gemm8w<1, 8><<<dim3(HID / BN, B_SAMPLES / BM), 512, 0, stream>>>(
        act0, wt3, sb3, act2, HID, 0, 0, rank, nullptr, nullptr);

    // selected experts (class-grouped, sorted-linear rows)
    gemm8w<2, 8><<<dim3(HID / BN, MAXT), 512, 0, stream>>>(
        act2, wtu0, ub0, act0, HID, (long)HID * HID, HID, nullptr, tclass, trow0);
    gemm8w<2, 8><<<dim3(HID / BN, MAXT), 512, 0, stream>>>(
        act0, wtu1, ub1, act1, HID, (long)HID * HID, HID, nullptr, tclass, trow0);
    gemm8w<2, 8><<<dim3(HID / BN, MAXT), 512, 0, stream>>>(
        act1, wtu2, ub2, act0, HID, (long)HID * HID, HID, nullptr, tclass, trow0);
    gemm8w<3, 8><<<dim3(1, MAXT), 512, 0, stream>>>(
        act0, wtu3, ub3, d_out, HID, (long)STYLE_D * HID, STYLE_D, order, tclass, trow0);
}